// Round 6
// baseline (1270.178 us; speedup 1.0000x reference)
//
#include <hip/hip_runtime.h>
#include <math.h>

// ---------------------------------------------------------------------------
// RecurrentEncoder: LSTM (B=256, D=2048, H=2048, T=32) + emission head (K=64)
// Round 9: 32x32x16 MFMA + K-split. R5's floor analysis: 2048 redundant
// ds_read_b128/tick (10.2 us) dominated. Now each wave = (row-tile rt 0..7,
// K-half kh 0..1): per step 1 A-load + 1 ds_read + 1 mfma_32x32x16 (B-read
// feeds 32 rows, not 16). LDS reads/tick halve to 1024. kh=1 waves write
// 32 KB fp32 partials to LDS; kh=0 waves reduce + run the gate epilogue.
// LDS = 128 KB W slab + 32 KB partials = 160 KB (CU max, 1 block/CU).
// 16 waves = 4/SIMD TLP retained (R5's proven lever).
// ---------------------------------------------------------------------------

typedef short  short8   __attribute__((ext_vector_type(8)));   // 8 x bf16
typedef float  floatx4  __attribute__((ext_vector_type(4)));
typedef float  floatx16 __attribute__((ext_vector_type(16)));

#define BB 256
#define HH 2048
#define G4 8192
#define KK 64
#define TT 32

__device__ __forceinline__ unsigned short f2bf(float f) {
  union { float f; unsigned int u; } v; v.f = f;
  unsigned int u = v.u;
  u += 0x7fffu + ((u >> 16) & 1u);   // round-to-nearest-even
  return (unsigned short)(u >> 16);
}
__device__ __forceinline__ float sigmoidf_(float x) { return 1.0f / (1.0f + __expf(-x)); }
__device__ __forceinline__ float softplusf_(float x) {
  return (x > 20.0f) ? x : log1pf(__expf(x));
}
__device__ __forceinline__ short8 cvt8(const float* __restrict__ s) {
  float4 a = reinterpret_cast<const float4*>(s)[0];
  float4 b = reinterpret_cast<const float4*>(s)[1];
  short8 o;
  o[0] = f2bf(a.x); o[1] = f2bf(a.y); o[2] = f2bf(a.z); o[3] = f2bf(a.w);
  o[4] = f2bf(b.x); o[5] = f2bf(b.y); o[6] = f2bf(b.z); o[7] = f2bf(b.w);
  return o;
}

// ---------------------------------------------------------------------------
// Weight transform: fp32 row-major [q or gate-major][K] ->
// bf16 chunks [blk][phase 2][k8 128][col 32][8elem]  (exact LDS slab layout).
// PERM=1: q = u*4+g  ->  src row g*2048+u  (LSTM gate interleave).
// ---------------------------------------------------------------------------
template <int PERM>
__global__ void cvt_w_kernel(const float* __restrict__ in,
                             unsigned short* __restrict__ out, int total) {
  int tid = blockIdx.x * 256 + threadIdx.x;
  if (tid >= total) return;
  int col = tid & 31;
  int k4  = (tid >> 5) & 63;    // pair index: k8 = 2*k4
  int ph  = (tid >> 11) & 1;
  int blk = tid >> 12;
  int q = blk * 32 + col;
  int srcrow = PERM ? ((q & 3) * HH + (q >> 2)) : q;
  const float* src = in + (size_t)srcrow * HH + (ph * 128 + k4 * 2) * 8;
  short8 o0 = cvt8(src);
  short8 o1 = cvt8(src + 8);
  size_t ch = ((size_t)(blk * 2 + ph) * 128 + k4 * 2) * 32 + col;
  reinterpret_cast<short8*>(out)[ch]      = o0;
  reinterpret_cast<short8*>(out)[ch + 32] = o1;
}

// x fp32 [256][2048] -> x^T chunks [k8 256][row 256][8]
__global__ void cvt_x_kernel(const float* __restrict__ in,
                             unsigned short* __restrict__ out) {
  int tid = blockIdx.x * 256 + threadIdx.x;   // 65536
  int row = tid & 255, k8 = tid >> 8;
  short8 o = cvt8(in + (size_t)row * HH + k8 * 8);
  reinterpret_cast<short8*>(out)[tid] = o;    // chunk = k8*256 + row
}

// ---------------------------------------------------------------------------
// Core GEMM (used by xg / fe): 256 rows x 32 cols x K2048. W staged via LDS
// in two 64 KB phases; A ring-prefetched depth 4. (512-thread, 8-wave form.)
// ---------------------------------------------------------------------------
__device__ __forceinline__ void core_gemm(const short8* __restrict__ A8,
                                          const short8* __restrict__ Wg8,
                                          short8* L8, floatx4 acc[2][2]) {
  const int tid = threadIdx.x;
  const int lane = tid & 63, wave = tid >> 6;
  const int l15 = lane & 15, l4 = lane >> 4;
  const short8* Lr = L8 + l4 * 32 + l15;          // + kt*128 + ct*16
  const int abase = l4 * 256 + wave * 32 + l15;   // chunk = k8*256 + row (+rt*16)
  for (int ph = 0; ph < 2; ++ph) {
    __syncthreads();   // protect slab from previous phase's readers
#pragma unroll
    for (int j = 0; j < 8; ++j)
      L8[tid + j * 512] = Wg8[ph * 4096 + tid + j * 512];
    __syncthreads();
    short8 Ar[4][2];
#pragma unroll
    for (int i = 0; i < 4; ++i) {
      Ar[i][0] = A8[abase +      (ph * 128 + i * 4) * 256];
      Ar[i][1] = A8[abase + 16 + (ph * 128 + i * 4) * 256];
    }
#pragma unroll
    for (int kt = 0; kt < 32; ++kt) {
      short8 a0 = Ar[kt & 3][0], a1 = Ar[kt & 3][1];
      if (kt < 28) {
        Ar[kt & 3][0] = A8[abase +      (ph * 128 + (kt + 4) * 4) * 256];
        Ar[kt & 3][1] = A8[abase + 16 + (ph * 128 + (kt + 4) * 4) * 256];
      }
      short8 b0 = Lr[kt * 128];
      short8 b1 = Lr[kt * 128 + 16];
      acc[0][0] = __builtin_amdgcn_mfma_f32_16x16x32_bf16(a0, b0, acc[0][0], 0, 0, 0);
      acc[0][1] = __builtin_amdgcn_mfma_f32_16x16x32_bf16(a0, b1, acc[0][1], 0, 0, 0);
      acc[1][0] = __builtin_amdgcn_mfma_f32_16x16x32_bf16(a1, b0, acc[1][0], 0, 0, 0);
      acc[1][1] = __builtin_amdgcn_mfma_f32_16x16x32_bf16(a1, b1, acc[1][1], 0, 0, 0);
    }
  }
}

// ---------------------------------------------------------------------------
// Persistent LSTM loop. 256 blocks x 1024 threads (16 waves = 4/SIMD), plain
// launch, 1 block/CU (LDS 160 KB). Wave = (rt = wave&7 row-tile of 32 rows,
// kh = wave>>3 K-half of 1024). Per tick (t>0), per wave: 64 steps of
// {1 A global load (ring-8), 1 B ds_read_b128 (ring-2), 1 mfma 32x32x16}
// -> kh=1 writes fp32 partials to LDS -> sync -> kh=0 reduces + epilogue
// (register c) -> h^T write -> device-scope grid barrier.
// 32x32x16 fragment maps: A row=l&31,k=8*(l>>5)+e; B col=l&31,k=8*(l>>5)+e;
// C/D col=l&31,row=(reg&3)+8*(reg>>2)+4*(l>>5)  [m74/m101-verified].
// ---------------------------------------------------------------------------
__global__ __launch_bounds__(1024) void lstm_loop_kernel(
    unsigned short* __restrict__ HallT, const unsigned short* __restrict__ Wt2,
    const float* __restrict__ xg, float* __restrict__ outh,
    float* __restrict__ outc, unsigned int* __restrict__ bar) {
  __shared__ __align__(16) unsigned short Wlds[65536];   // 128 KB W slab
  __shared__ __align__(16) float Rlds[8192];             // 32 KB partials
  const int tid = threadIdx.x;
  const int lane = tid & 63, wave = tid >> 6;   // wave 0..15
  const int rt = wave & 7, kh = wave >> 3;
  const int l31 = lane & 31, l5 = lane >> 5;
  const int qb = blockIdx.x * 32;
  const int gate = lane & 3;                    // = (qb + l31) & 3
  const int base = lane & ~3;

  // xg is tick-invariant: load ONCE into registers (issue before LDS fill so
  // the latency hides under it). Loaded by all waves (uniform, no divergence);
  // only kh=0 uses it.
  float xgr[4][4];
#pragma unroll
  for (int q4 = 0; q4 < 4; ++q4)
#pragma unroll
    for (int r = 0; r < 4; ++r) {
      const int row = rt * 32 + r + 8 * q4 + 4 * l5;
      xgr[q4][r] = xg[(size_t)row * G4 + qb + l31];
    }

  short8* L8 = reinterpret_cast<short8*>(Wlds);
  {
    const short8* Wg8 = reinterpret_cast<const short8*>(Wt2)
                        + (size_t)blockIdx.x * 8192;
#pragma unroll
    for (int j = 0; j < 8; ++j)
      L8[tid + j * 1024] = Wg8[tid + j * 1024];
  }
  __syncthreads();

  // B: chunk(k8,col) = k8*32+col with k8 = kh*128 + step*2 + l5, col = l31
  //    -> index = kh*4096 + step*64 + lane  (stride-1 across lanes).
  const short8* Lb = L8 + kh * 4096 + lane;
  // A: chunk = k8*256 + row, row = rt*32 + l31.
  const int abase = (kh * 128 + l5) * 256 + rt * 32 + l31;

  // Cell state: tick-carried, block-private -> registers (gate==0 lanes of
  // kh=0 waves hold the live values; other lanes carry dead copies).
  float creg[4][4];
#pragma unroll
  for (int q4 = 0; q4 < 4; ++q4)
#pragma unroll
    for (int r = 0; r < 4; ++r) creg[q4][r] = 0.0f;

  float4* R4 = reinterpret_cast<float4*>(Rlds);

#pragma unroll 1
  for (int t = 0; t < TT; ++t) {
    unsigned short* Hout = HallT + (size_t)(t + 1) * 524288;

    floatx16 acc = {0.f, 0.f, 0.f, 0.f, 0.f, 0.f, 0.f, 0.f,
                    0.f, 0.f, 0.f, 0.f, 0.f, 0.f, 0.f, 0.f};

    if (t > 0) {   // t==0: h0 = 0 -> GEMM contributes nothing
      const short8* Ap = reinterpret_cast<const short8*>(HallT)
                         + (size_t)t * 65536 + abase;
      // Depth-8 A ring (32 VGPR) + 2-deep B ring; 4 waves/SIMD TLP covers
      // the rest of the post-barrier latency.
      short8 Ar[8];
#pragma unroll
      for (int i = 0; i < 8; ++i) Ar[i] = Ap[i * 512];
      short8 Brg[2];
      Brg[0] = Lb[0];
#pragma unroll
      for (int step = 0; step < 64; ++step) {
        short8 a = Ar[step & 7];
        short8 b = Brg[step & 1];
        if (step < 63) Brg[(step + 1) & 1] = Lb[(step + 1) * 64];
        if (step < 56) Ar[step & 7] = Ap[(step + 8) * 512];
        acc = __builtin_amdgcn_mfma_f32_32x32x16_bf16(a, b, acc, 0, 0, 0);
      }

      // Cross-wave K reduction: kh=1 writes partial tile, kh=0 accumulates.
      if (kh == 1) {
#pragma unroll
        for (int q4 = 0; q4 < 4; ++q4) {
          float4 v = {acc[4 * q4], acc[4 * q4 + 1], acc[4 * q4 + 2], acc[4 * q4 + 3]};
          R4[rt * 256 + q4 * 64 + lane] = v;
        }
      }
      __syncthreads();
      if (kh == 0) {
#pragma unroll
        for (int q4 = 0; q4 < 4; ++q4) {
          float4 v = R4[rt * 256 + q4 * 64 + lane];
          acc[4 * q4]     += v.x;
          acc[4 * q4 + 1] += v.y;
          acc[4 * q4 + 2] += v.z;
          acc[4 * q4 + 3] += v.w;
        }
      }
    }

    if (kh == 0) {
      const int last = (t == TT - 1);
      const int u7 = l31 >> 2;   // unit within block's 8
#pragma unroll
      for (int q4 = 0; q4 < 4; ++q4)
#pragma unroll
        for (int r = 0; r < 4; ++r) {
          const int row = rt * 32 + r + 8 * q4 + 4 * l5;
          float g = acc[q4 * 4 + r] + xgr[q4][r];
          float act = (gate == 2) ? tanhf(g) : sigmoidf_(g);
          float iv = __shfl(act, base);
          float fv = __shfl(act, base + 1);
          float gv = __shfl(act, base + 2);
          float ov = __shfl(act, base + 3);
          if (gate == 0) {
            float cnew = fv * creg[q4][r] + iv * gv;
            float hnew = ov * tanhf(cnew);
            creg[q4][r] = cnew;
            Hout[(size_t)(blockIdx.x * 256 + row) * 8 + u7] = f2bf(hnew);
            if (last) {
              const size_t ci = (size_t)row * HH + blockIdx.x * 8 + u7;
              outh[ci] = hnew; outc[ci] = cnew;
            }
          }
        }
    }

    if (t < TT - 1) {
      // ---- device-scope grid barrier (all 256 blocks resident, 1/CU) ----
      __syncthreads();   // drains vmcnt(0): all waves' h stores are in L2
      if (tid == 0) {
        __hip_atomic_fetch_add(bar, 1u, __ATOMIC_RELEASE,
                               __HIP_MEMORY_SCOPE_AGENT);
        const unsigned int target = (unsigned int)(t + 1) * 256u;
        while (__hip_atomic_load(bar, __ATOMIC_ACQUIRE,
                                 __HIP_MEMORY_SCOPE_AGENT) < target)
          __builtin_amdgcn_s_sleep(2);
      }
      __syncthreads();
    }
  }
}

// xg = x @ W_ih^T (q-permuted cols) + b_ih + b_hh
__global__ __launch_bounds__(512) void xg_kernel(
    const unsigned short* __restrict__ XT, const unsigned short* __restrict__ Wih,
    const float* __restrict__ b_ih, const float* __restrict__ b_hh,
    float* __restrict__ xg) {
  __shared__ __align__(16) unsigned short Wlds[32768];
  floatx4 acc[2][2];
  floatx4 z4 = {0.f, 0.f, 0.f, 0.f};
  acc[0][0] = z4; acc[0][1] = z4; acc[1][0] = z4; acc[1][1] = z4;
  core_gemm(reinterpret_cast<const short8*>(XT),
            reinterpret_cast<const short8*>(Wih) + (size_t)blockIdx.x * 8192,
            reinterpret_cast<short8*>(Wlds), acc);

  const int tid = threadIdx.x, lane = tid & 63, wave = tid >> 6;
  const int l15 = lane & 15, l4 = lane >> 4;
  const int qb = blockIdx.x * 32, rw = wave * 32;
#pragma unroll
  for (int rt = 0; rt < 2; ++rt)
#pragma unroll
    for (int ct = 0; ct < 2; ++ct) {
      const int q = qb + ct * 16 + l15;
      const float bias = b_ih[(q & 3) * HH + (q >> 2)] + b_hh[(q & 3) * HH + (q >> 2)];
#pragma unroll
      for (int r = 0; r < 4; ++r) {
        const int row = rw + rt * 16 + l4 * 4 + r;
        xg[(size_t)row * G4 + q] = acc[rt][ct][r] + bias;
      }
    }
}

// fe = h_t @ W_fe^T + b_fe for all t: block = (t, colgroup of 32)
__global__ __launch_bounds__(512) void fe_kernel(
    const unsigned short* __restrict__ HallT, const unsigned short* __restrict__ Wfe,
    const float* __restrict__ b_fe, float* __restrict__ fe) {
  const int t = blockIdx.x >> 2, cg_ = blockIdx.x & 3;
  __shared__ __align__(16) unsigned short Wlds[32768];
  floatx4 acc[2][2];
  floatx4 z4 = {0.f, 0.f, 0.f, 0.f};
  acc[0][0] = z4; acc[0][1] = z4; acc[1][0] = z4; acc[1][1] = z4;
  core_gemm(reinterpret_cast<const short8*>(HallT) + (size_t)(t + 1) * 65536,
            reinterpret_cast<const short8*>(Wfe) + (size_t)cg_ * 8192,
            reinterpret_cast<short8*>(Wlds), acc);

  const int tid = threadIdx.x, lane = tid & 63, wave = tid >> 6;
  const int l15 = lane & 15, l4 = lane >> 4;
  const int rw = wave * 32;
#pragma unroll
  for (int rt = 0; rt < 2; ++rt)
#pragma unroll
    for (int ct = 0; ct < 2; ++ct) {
      const int col = cg_ * 32 + ct * 16 + l15;
      const float bias = b_fe[col];
#pragma unroll
      for (int r = 0; r < 4; ++r) {
        const int row = rw + rt * 16 + l4 * 4 + r;
        fe[((size_t)t * 256 + row) * 128 + col] = acc[rt][ct][r] + bias;
      }
    }
}

// z = eps*softplus(fe[:,64:]-5) + fe[:,:64]; outputs laid out (B,K,T)
__global__ void z_kernel(const float* __restrict__ eps, const float* __restrict__ fe,
                         float* __restrict__ out) {
  const int tid = blockIdx.x * blockDim.x + threadIdx.x;  // 524288 = T*B*K
  const int tt = tid >> 14;
  const int b = (tid >> 6) & 255;
  const int k = tid & 63;
  const int frow = tt * 256 + b;
  const float mus = fe[frow * 128 + k];
  const float sig = softplusf_(fe[frow * 128 + 64 + k] - 5.0f);
  const float z = eps[tid] * sig + mus;
  const int o = (b * KK + k) * TT + tt;
  out[o] = z;
  out[524288 + o] = mus;
  out[2 * 524288 + o] = sig;
}

extern "C" void kernel_launch(void* const* d_in, const int* in_sizes, int n_in,
                              void* d_out, int out_size, void* d_ws, size_t ws_size,
                              hipStream_t stream) {
  const float* x    = (const float*)d_in[0];
  const float* eps  = (const float*)d_in[1];
  const float* W_ih = (const float*)d_in[2];
  const float* W_hh = (const float*)d_in[3];
  const float* b_ih = (const float*)d_in[4];
  const float* b_hh = (const float*)d_in[5];
  const float* W_fe = (const float*)d_in[6];
  const float* b_fe = (const float*)d_in[7];
  float* out = (float*)d_out;

  const size_t BH  = (size_t)BB * HH;       // 524288
  const size_t BKT = (size_t)BB * KK * TT;  // 524288

  char* p = (char*)d_ws;
  auto nxt = [&](size_t bytes) -> char* {
    char* r = p; p += (bytes + 255) & ~(size_t)255; return r;
  };
  unsigned short* Wbig  = (unsigned short*)nxt((size_t)G4 * HH * 2);       // 32 MB, W_ih then W_hh
  float*          xg    = (float*)nxt((size_t)BB * G4 * 4);                // 8 MB
  unsigned short* HallT = (unsigned short*)nxt((size_t)(TT + 1) * BH * 2); // 33 MB
  unsigned short* XT    = (unsigned short*)nxt(BH * 2);                    // 1 MB
  unsigned short* Wfeb  = (unsigned short*)nxt((size_t)128 * HH * 2);      // 0.5 MB
  float*          fe    = (float*)nxt((size_t)(TT * BB) * 128 * 4);        // 4 MB
  unsigned int*   bar   = (unsigned int*)nxt(256);                         // grid barrier

  hipMemsetAsync(bar, 0, 256, stream);

  cvt_x_kernel<<<256, 256, 0, stream>>>(x, XT);
  cvt_w_kernel<0><<<64, 256, 0, stream>>>(W_fe, Wfeb, 16384);
  cvt_w_kernel<1><<<4096, 256, 0, stream>>>(W_ih, Wbig, 1048576);
  xg_kernel<<<256, 512, 0, stream>>>(XT, Wbig, b_ih, b_hh, xg);
  cvt_w_kernel<1><<<4096, 256, 0, stream>>>(W_hh, Wbig, 1048576);

  lstm_loop_kernel<<<256, 1024, 0, stream>>>(
      HallT, Wbig, xg, out + 3 * BKT, out + 3 * BKT + BH, bar);

  fe_kernel<<<128, 512, 0, stream>>>(HallT, Wfeb, b_fe, fe);
  z_kernel<<<2048, 256, 0, stream>>>(eps, fe, out);
}

// Round 7
// 1051.476 us; speedup vs baseline: 1.2080x; 1.2080x over previous
//
#include <hip/hip_runtime.h>
#include <math.h>

// ---------------------------------------------------------------------------
// RecurrentEncoder: LSTM (B=256, D=2048, H=2048, T=32) + emission head (K=64)
// Round 10: revert to R5 structure (best-known: 16 waves, 16x16x32, per-wave
// 16x32 tile, depth-8 A ring) — the R9 K-split regressed (LDS reads were not
// binding). Changes vs R5:
//  - two-level barrier arrival (32 group counters -> 1 global) kills the
//    256-RMW-on-one-line serialization; relaxed spin + ONE final acquire
//    (acquire-per-poll invalidate storm removed).
//  - explicit depth-4 B-ring (3-ahead ds_read prefetch).
//  - __launch_bounds__(1024,4): VGPR cap 64->128 so both rings stay live.
// ---------------------------------------------------------------------------

typedef short  short8  __attribute__((ext_vector_type(8)));   // 8 x bf16
typedef float  floatx4 __attribute__((ext_vector_type(4)));

#define BB 256
#define HH 2048
#define G4 8192
#define KK 64
#define TT 32

__device__ __forceinline__ unsigned short f2bf(float f) {
  union { float f; unsigned int u; } v; v.f = f;
  unsigned int u = v.u;
  u += 0x7fffu + ((u >> 16) & 1u);   // round-to-nearest-even
  return (unsigned short)(u >> 16);
}
__device__ __forceinline__ float sigmoidf_(float x) { return 1.0f / (1.0f + __expf(-x)); }
__device__ __forceinline__ float softplusf_(float x) {
  return (x > 20.0f) ? x : log1pf(__expf(x));
}
__device__ __forceinline__ short8 cvt8(const float* __restrict__ s) {
  float4 a = reinterpret_cast<const float4*>(s)[0];
  float4 b = reinterpret_cast<const float4*>(s)[1];
  short8 o;
  o[0] = f2bf(a.x); o[1] = f2bf(a.y); o[2] = f2bf(a.z); o[3] = f2bf(a.w);
  o[4] = f2bf(b.x); o[5] = f2bf(b.y); o[6] = f2bf(b.z); o[7] = f2bf(b.w);
  return o;
}

// ---------------------------------------------------------------------------
// Weight transform: fp32 row-major [q or gate-major][K] ->
// bf16 chunks [blk][phase 2][k8 128][col 32][8elem]  (exact LDS slab layout).
// PERM=1: q = u*4+g  ->  src row g*2048+u  (LSTM gate interleave).
// ---------------------------------------------------------------------------
template <int PERM>
__global__ void cvt_w_kernel(const float* __restrict__ in,
                             unsigned short* __restrict__ out, int total) {
  int tid = blockIdx.x * 256 + threadIdx.x;
  if (tid >= total) return;
  int col = tid & 31;
  int k4  = (tid >> 5) & 63;    // pair index: k8 = 2*k4
  int ph  = (tid >> 11) & 1;
  int blk = tid >> 12;
  int q = blk * 32 + col;
  int srcrow = PERM ? ((q & 3) * HH + (q >> 2)) : q;
  const float* src = in + (size_t)srcrow * HH + (ph * 128 + k4 * 2) * 8;
  short8 o0 = cvt8(src);
  short8 o1 = cvt8(src + 8);
  size_t ch = ((size_t)(blk * 2 + ph) * 128 + k4 * 2) * 32 + col;
  reinterpret_cast<short8*>(out)[ch]      = o0;
  reinterpret_cast<short8*>(out)[ch + 32] = o1;
}

// x fp32 [256][2048] -> x^T chunks [k8 256][row 256][8]
__global__ void cvt_x_kernel(const float* __restrict__ in,
                             unsigned short* __restrict__ out) {
  int tid = blockIdx.x * 256 + threadIdx.x;   // 65536
  int row = tid & 255, k8 = tid >> 8;
  short8 o = cvt8(in + (size_t)row * HH + k8 * 8);
  reinterpret_cast<short8*>(out)[tid] = o;    // chunk = k8*256 + row
}

// ---------------------------------------------------------------------------
// Core GEMM (used by xg / fe): 256 rows x 32 cols x K2048. W staged via LDS
// in two 64 KB phases; A ring-prefetched depth 4. (512-thread, 8-wave form.)
// ---------------------------------------------------------------------------
__device__ __forceinline__ void core_gemm(const short8* __restrict__ A8,
                                          const short8* __restrict__ Wg8,
                                          short8* L8, floatx4 acc[2][2]) {
  const int tid = threadIdx.x;
  const int lane = tid & 63, wave = tid >> 6;
  const int l15 = lane & 15, l4 = lane >> 4;
  const short8* Lr = L8 + l4 * 32 + l15;          // + kt*128 + ct*16
  const int abase = l4 * 256 + wave * 32 + l15;   // chunk = k8*256 + row (+rt*16)
  for (int ph = 0; ph < 2; ++ph) {
    __syncthreads();   // protect slab from previous phase's readers
#pragma unroll
    for (int j = 0; j < 8; ++j)
      L8[tid + j * 512] = Wg8[ph * 4096 + tid + j * 512];
    __syncthreads();
    short8 Ar[4][2];
#pragma unroll
    for (int i = 0; i < 4; ++i) {
      Ar[i][0] = A8[abase +      (ph * 128 + i * 4) * 256];
      Ar[i][1] = A8[abase + 16 + (ph * 128 + i * 4) * 256];
    }
#pragma unroll
    for (int kt = 0; kt < 32; ++kt) {
      short8 a0 = Ar[kt & 3][0], a1 = Ar[kt & 3][1];
      if (kt < 28) {
        Ar[kt & 3][0] = A8[abase +      (ph * 128 + (kt + 4) * 4) * 256];
        Ar[kt & 3][1] = A8[abase + 16 + (ph * 128 + (kt + 4) * 4) * 256];
      }
      short8 b0 = Lr[kt * 128];
      short8 b1 = Lr[kt * 128 + 16];
      acc[0][0] = __builtin_amdgcn_mfma_f32_16x16x32_bf16(a0, b0, acc[0][0], 0, 0, 0);
      acc[0][1] = __builtin_amdgcn_mfma_f32_16x16x32_bf16(a0, b1, acc[0][1], 0, 0, 0);
      acc[1][0] = __builtin_amdgcn_mfma_f32_16x16x32_bf16(a1, b0, acc[1][0], 0, 0, 0);
      acc[1][1] = __builtin_amdgcn_mfma_f32_16x16x32_bf16(a1, b1, acc[1][1], 0, 0, 0);
    }
  }
}

// ---------------------------------------------------------------------------
// Persistent LSTM loop. 256 blocks x 1024 threads (16 waves = 4/SIMD), plain
// launch, 1 block/CU (128 KB LDS). Per tick (t>0): per-wave 16x32 tile,
// depth-8 A ring + depth-4 B ring, 2 MFMA/kt -> gate epilogue (register c)
// -> h^T write -> two-level device-scope grid barrier.
// ---------------------------------------------------------------------------
__global__ __launch_bounds__(1024, 4) void lstm_loop_kernel(
    unsigned short* __restrict__ HallT, const unsigned short* __restrict__ Wt2,
    const float* __restrict__ xg, float* __restrict__ outh,
    float* __restrict__ outc, unsigned int* __restrict__ bar) {
  __shared__ __align__(16) unsigned short Wlds[65536];   // 128 KB
  const int tid = threadIdx.x;
  const int lane = tid & 63, wave = tid >> 6;   // wave 0..15
  const int l15 = lane & 15, l4 = lane >> 4;
  const int qb = blockIdx.x * 32, rw = wave * 16;
  const int gate = l15 & 3;
  const int base = lane & ~3;

  // xg is tick-invariant: load ONCE into registers.
  float xgr[2][4];
#pragma unroll
  for (int ct = 0; ct < 2; ++ct) {
    const int q = qb + ct * 16 + l15;
#pragma unroll
    for (int r = 0; r < 4; ++r) {
      const int row = rw + l4 * 4 + r;
      xgr[ct][r] = xg[(size_t)row * G4 + q];
    }
  }

  short8* L8 = reinterpret_cast<short8*>(Wlds);
  {
    const short8* Wg8 = reinterpret_cast<const short8*>(Wt2)
                        + (size_t)blockIdx.x * 8192;
#pragma unroll
    for (int j = 0; j < 8; ++j)
      L8[tid + j * 1024] = Wg8[tid + j * 1024];
  }
  __syncthreads();

  const short8* Lr = L8 + l4 * 32 + l15;          // + kt*128 + ct*16
  const int abase = l4 * 256 + wave * 16 + l15;   // chunk = k8*256 + row

  // Cell state: tick-carried, block-private -> registers.
  float creg[2][4];
#pragma unroll
  for (int ct = 0; ct < 2; ++ct)
#pragma unroll
    for (int r = 0; r < 4; ++r) creg[ct][r] = 0.0f;

#pragma unroll 1
  for (int t = 0; t < TT; ++t) {
    unsigned short* Hout = HallT + (size_t)(t + 1) * 524288;

    floatx4 acc[2];
    floatx4 z4 = {0.f, 0.f, 0.f, 0.f};
    acc[0] = z4; acc[1] = z4;

    if (t > 0) {   // t==0: h0 = 0 -> GEMM contributes nothing
      const short8* Ap = reinterpret_cast<const short8*>(HallT)
                         + (size_t)t * 65536 + abase;
      // Depth-8 A ring (32 VGPR) + depth-4 B ring (32 VGPR); 4 waves/SIMD
      // TLP covers residual latency. __launch_bounds__(1024,4) caps VGPR at
      // 128 so neither ring gets collapsed/spilled.
      short8 Ar[8];
#pragma unroll
      for (int i = 0; i < 8; ++i) Ar[i] = Ap[i * 1024];
      short8 Brg[4][2];
#pragma unroll
      for (int i = 0; i < 3; ++i) {
        Brg[i][0] = Lr[i * 128];
        Brg[i][1] = Lr[i * 128 + 16];
      }
#pragma unroll
      for (int kt = 0; kt < 64; ++kt) {
        short8 a0 = Ar[kt & 7];
        short8 b0 = Brg[kt & 3][0];
        short8 b1 = Brg[kt & 3][1];
        if (kt < 61) {
          Brg[(kt + 3) & 3][0] = Lr[(kt + 3) * 128];
          Brg[(kt + 3) & 3][1] = Lr[(kt + 3) * 128 + 16];
        }
        if (kt < 56) Ar[kt & 7] = Ap[(kt + 8) * 1024];
        acc[0] = __builtin_amdgcn_mfma_f32_16x16x32_bf16(a0, b0, acc[0], 0, 0, 0);
        acc[1] = __builtin_amdgcn_mfma_f32_16x16x32_bf16(a0, b1, acc[1], 0, 0, 0);
      }
    }

    const int last = (t == TT - 1);
#pragma unroll
    for (int ct = 0; ct < 2; ++ct) {
      const floatx4 av = acc[ct];
      const int q = qb + ct * 16 + l15;
      const int u = q >> 2;
#pragma unroll
      for (int r = 0; r < 4; ++r) {
        const int row = rw + l4 * 4 + r;
        float g = av[r] + xgr[ct][r];
        float act = (gate == 2) ? tanhf(g) : sigmoidf_(g);
        float iv = __shfl(act, base);
        float fv = __shfl(act, base + 1);
        float gv = __shfl(act, base + 2);
        float ov = __shfl(act, base + 3);
        if (gate == 0) {
          float cnew = fv * creg[ct][r] + iv * gv;
          float hnew = ov * tanhf(cnew);
          creg[ct][r] = cnew;
          Hout[(size_t)(blockIdx.x * 256 + row) * 8 + (u & 7)] = f2bf(hnew);
          if (last) {
            const size_t ci = (size_t)row * HH + u;
            outh[ci] = hnew; outc[ci] = cnew;
          }
        }
      }
    }

    if (t < TT - 1) {
      // ---- two-level device-scope grid barrier (256 blocks, 1/CU) ----
      // bar[0]: global counter (32 increments/tick, one per group leader)
      // bar[16 + g*16]: group g counter (8 blocks/group, own cache line)
      __syncthreads();   // drains vmcnt(0): all waves' h stores are in L2
      if (tid == 0) {
        const int g = blockIdx.x >> 3;
        unsigned int old = __hip_atomic_fetch_add(
            &bar[16 + g * 16], 1u, __ATOMIC_ACQ_REL, __HIP_MEMORY_SCOPE_AGENT);
        if ((old & 7u) == 7u)   // last of the 8-block group this tick
          __hip_atomic_fetch_add(&bar[0], 1u, __ATOMIC_RELEASE,
                                 __HIP_MEMORY_SCOPE_AGENT);
        const unsigned int target = (unsigned int)(t + 1) * 32u;
        while (__hip_atomic_load(&bar[0], __ATOMIC_RELAXED,
                                 __HIP_MEMORY_SCOPE_AGENT) < target)
          __builtin_amdgcn_s_sleep(2);
        // single acquire: fence + cache-invalidate once, not per poll
        (void)__hip_atomic_load(&bar[0], __ATOMIC_ACQUIRE,
                                __HIP_MEMORY_SCOPE_AGENT);
      }
      __syncthreads();
    }
  }
}

// xg = x @ W_ih^T (q-permuted cols) + b_ih + b_hh
__global__ __launch_bounds__(512) void xg_kernel(
    const unsigned short* __restrict__ XT, const unsigned short* __restrict__ Wih,
    const float* __restrict__ b_ih, const float* __restrict__ b_hh,
    float* __restrict__ xg) {
  __shared__ __align__(16) unsigned short Wlds[32768];
  floatx4 acc[2][2];
  floatx4 z4 = {0.f, 0.f, 0.f, 0.f};
  acc[0][0] = z4; acc[0][1] = z4; acc[1][0] = z4; acc[1][1] = z4;
  core_gemm(reinterpret_cast<const short8*>(XT),
            reinterpret_cast<const short8*>(Wih) + (size_t)blockIdx.x * 8192,
            reinterpret_cast<short8*>(Wlds), acc);

  const int tid = threadIdx.x, lane = tid & 63, wave = tid >> 6;
  const int l15 = lane & 15, l4 = lane >> 4;
  const int qb = blockIdx.x * 32, rw = wave * 32;
#pragma unroll
  for (int rt = 0; rt < 2; ++rt)
#pragma unroll
    for (int ct = 0; ct < 2; ++ct) {
      const int q = qb + ct * 16 + l15;
      const float bias = b_ih[(q & 3) * HH + (q >> 2)] + b_hh[(q & 3) * HH + (q >> 2)];
#pragma unroll
      for (int r = 0; r < 4; ++r) {
        const int row = rw + rt * 16 + l4 * 4 + r;
        xg[(size_t)row * G4 + q] = acc[rt][ct][r] + bias;
      }
    }
}

// fe = h_t @ W_fe^T + b_fe for all t: block = (t, colgroup of 32)
__global__ __launch_bounds__(512) void fe_kernel(
    const unsigned short* __restrict__ HallT, const unsigned short* __restrict__ Wfe,
    const float* __restrict__ b_fe, float* __restrict__ fe) {
  const int t = blockIdx.x >> 2, cg_ = blockIdx.x & 3;
  __shared__ __align__(16) unsigned short Wlds[32768];
  floatx4 acc[2][2];
  floatx4 z4 = {0.f, 0.f, 0.f, 0.f};
  acc[0][0] = z4; acc[0][1] = z4; acc[1][0] = z4; acc[1][1] = z4;
  core_gemm(reinterpret_cast<const short8*>(HallT) + (size_t)(t + 1) * 65536,
            reinterpret_cast<const short8*>(Wfe) + (size_t)cg_ * 8192,
            reinterpret_cast<short8*>(Wlds), acc);

  const int tid = threadIdx.x, lane = tid & 63, wave = tid >> 6;
  const int l15 = lane & 15, l4 = lane >> 4;
  const int rw = wave * 32;
#pragma unroll
  for (int rt = 0; rt < 2; ++rt)
#pragma unroll
    for (int ct = 0; ct < 2; ++ct) {
      const int col = cg_ * 32 + ct * 16 + l15;
      const float bias = b_fe[col];
#pragma unroll
      for (int r = 0; r < 4; ++r) {
        const int row = rw + rt * 16 + l4 * 4 + r;
        fe[((size_t)t * 256 + row) * 128 + col] = acc[rt][ct][r] + bias;
      }
    }
}

// z = eps*softplus(fe[:,64:]-5) + fe[:,:64]; outputs laid out (B,K,T)
__global__ void z_kernel(const float* __restrict__ eps, const float* __restrict__ fe,
                         float* __restrict__ out) {
  const int tid = blockIdx.x * blockDim.x + threadIdx.x;  // 524288 = T*B*K
  const int tt = tid >> 14;
  const int b = (tid >> 6) & 255;
  const int k = tid & 63;
  const int frow = tt * 256 + b;
  const float mus = fe[frow * 128 + k];
  const float sig = softplusf_(fe[frow * 128 + 64 + k] - 5.0f);
  const float z = eps[tid] * sig + mus;
  const int o = (b * KK + k) * TT + tt;
  out[o] = z;
  out[524288 + o] = mus;
  out[2 * 524288 + o] = sig;
}

extern "C" void kernel_launch(void* const* d_in, const int* in_sizes, int n_in,
                              void* d_out, int out_size, void* d_ws, size_t ws_size,
                              hipStream_t stream) {
  const float* x    = (const float*)d_in[0];
  const float* eps  = (const float*)d_in[1];
  const float* W_ih = (const float*)d_in[2];
  const float* W_hh = (const float*)d_in[3];
  const float* b_ih = (const float*)d_in[4];
  const float* b_hh = (const float*)d_in[5];
  const float* W_fe = (const float*)d_in[6];
  const float* b_fe = (const float*)d_in[7];
  float* out = (float*)d_out;

  const size_t BH  = (size_t)BB * HH;       // 524288
  const size_t BKT = (size_t)BB * KK * TT;  // 524288

  char* p = (char*)d_ws;
  auto nxt = [&](size_t bytes) -> char* {
    char* r = p; p += (bytes + 255) & ~(size_t)255; return r;
  };
  unsigned short* Wbig  = (unsigned short*)nxt((size_t)G4 * HH * 2);       // 32 MB, W_ih then W_hh
  float*          xg    = (float*)nxt((size_t)BB * G4 * 4);                // 8 MB
  unsigned short* HallT = (unsigned short*)nxt((size_t)(TT + 1) * BH * 2); // 33 MB
  unsigned short* XT    = (unsigned short*)nxt(BH * 2);                    // 1 MB
  unsigned short* Wfeb  = (unsigned short*)nxt((size_t)128 * HH * 2);      // 0.5 MB
  float*          fe    = (float*)nxt((size_t)(TT * BB) * 128 * 4);        // 4 MB
  unsigned int*   bar   = (unsigned int*)nxt(4096);                        // barrier tree

  hipMemsetAsync(bar, 0, 4096, stream);

  cvt_x_kernel<<<256, 256, 0, stream>>>(x, XT);
  cvt_w_kernel<0><<<64, 256, 0, stream>>>(W_fe, Wfeb, 16384);
  cvt_w_kernel<1><<<4096, 256, 0, stream>>>(W_ih, Wbig, 1048576);
  xg_kernel<<<256, 512, 0, stream>>>(XT, Wbig, b_ih, b_hh, xg);
  cvt_w_kernel<1><<<4096, 256, 0, stream>>>(W_hh, Wbig, 1048576);

  lstm_loop_kernel<<<256, 1024, 0, stream>>>(
      HallT, Wbig, xg, out + 3 * BKT, out + 3 * BKT + BH, bar);

  fe_kernel<<<128, 512, 0, stream>>>(HallT, Wfeb, b_fe, fe);
  z_kernel<<<2048, 256, 0, stream>>>(eps, fe, out);
}